// Round 1
// baseline (557.644 us; speedup 1.0000x reference)
//
#include <hip/hip_runtime.h>

#define DEVI __device__ __forceinline__

typedef __bf16 v8bf __attribute__((ext_vector_type(8)));
typedef float f32x4 __attribute__((ext_vector_type(4)));
typedef int int4v __attribute__((ext_vector_type(4)));

constexpr int B_  = 2;
constexpr int C_  = 96;
constexpr int IMG = 256;
constexpr int N_  = 16384;   // tokens
constexpr int TD  = 384;
constexpr int H_  = 6;
constexpr int G_  = 50;

DEVI short f2bf(float f){
  unsigned u = __builtin_bit_cast(unsigned, f);
  u = (u + 0x7fffu + ((u >> 16) & 1u)) >> 16;
  return (short)u;
}
DEVI float bf2f(short s){
  return __builtin_bit_cast(float, ((unsigned)(unsigned short)s) << 16);
}
DEVI int gpos(int g){ return (16383 * g) / 49; }   // matches np.linspace(0,16383,50).astype(int32)

DEVI f32x4 mfma16(v8bf a, v8bf b, f32x4 c){
  return __builtin_amdgcn_mfma_f32_16x16x32_bf16(a, b, c, 0, 0, 0);
}

// ---------------- prep: W (k-major f32) -> Wt (n-major bf16) for 5 GEMM weights ----
__global__ void prep_w(const float* __restrict__ w0, const float* __restrict__ w1,
                       const float* __restrict__ w2, const float* __restrict__ w3,
                       const float* __restrict__ w4, short* __restrict__ Wt){
  int z = blockIdx.y;
  const float* W = z==0 ? w0 : z==1 ? w1 : z==2 ? w2 : z==3 ? w3 : w4;
  int idx = blockIdx.x * 256 + threadIdx.x;      // idx = n*384 + k
  int n = idx / TD, k = idx % TD;
  Wt[z*TD*TD + idx] = f2bf(W[k*TD + n]);
}

// ---------------- tokenize: x f32 -> tokens bf16 (B,N,TD) ------------------------
__global__ void tokenize(const float* __restrict__ x, short* __restrict__ tokens){
  int idx = blockIdx.x * 256 + threadIdx.x;      // B*N*TD/8 threads
  int t8 = idx % (TD/8);
  int bn = idx / (TD/8);
  int n = bn % N_, b = bn / N_;
  int t0 = t8 * 8;
  int i0 = (n >> 7) * 2, j0 = (n & 127) * 2;
  short o[8];
  #pragma unroll
  for (int e = 0; e < 8; e++){
    int t = t0 + e;
    int c = t >> 2, wi = (t >> 1) & 1, wj = t & 1;
    o[e] = f2bf(x[((b*C_ + c)*IMG + i0 + wi)*IMG + j0 + wj]);
  }
  *reinterpret_cast<int4v*>(tokens + bn*TD + t0) = *reinterpret_cast<int4v*>(o);
}

// ---------------- 5-way projection GEMM: tokens(32768x384) @ W(384x384)+bias ------
__global__ __launch_bounds__(256) void gemm_proj(
    const short* __restrict__ A, const short* __restrict__ Wt,
    const float* __restrict__ bq, const float* __restrict__ bk, const float* __restrict__ bv,
    const float* __restrict__ bkg, const float* __restrict__ bvg,
    short* __restrict__ qbuf, short* __restrict__ kbuf, short* __restrict__ vbuf,
    short* __restrict__ kgabuf, short* __restrict__ vgabuf)
{
  __shared__ short sA[128][72];
  __shared__ short sB[128][72];
  int z = blockIdx.z;
  const float* bias = z==0 ? bq : z==1 ? bk : z==2 ? bv : z==3 ? bkg : bvg;
  short* out = z==0 ? qbuf : z==1 ? kbuf : z==2 ? vbuf : z==3 ? kgabuf : vgabuf;
  const short* Wz = Wt + z*TD*TD;
  int m0 = blockIdx.x * 128, n0 = blockIdx.y * 128;
  int tid = threadIdx.x, l = tid & 63, w = tid >> 6;
  int wm = w >> 1, wn = w & 1;
  f32x4 acc[4][4] = {};
  for (int k0 = 0; k0 < TD; k0 += 64){
    #pragma unroll
    for (int i = 0; i < 4; i++){
      int ch = i*256 + tid; int row = ch >> 3, cb = (ch & 7) * 8;
      int4v va = *reinterpret_cast<const int4v*>(A  + (m0+row)*TD + k0 + cb);
      int4v vb = *reinterpret_cast<const int4v*>(Wz + (n0+row)*TD + k0 + cb);
      *reinterpret_cast<int4v*>(&sA[row][cb]) = va;
      *reinterpret_cast<int4v*>(&sB[row][cb]) = vb;
    }
    __syncthreads();
    #pragma unroll
    for (int ks = 0; ks < 2; ks++){
      v8bf af[4], bfr[4];
      #pragma unroll
      for (int i = 0; i < 4; i++){
        af[i]  = *reinterpret_cast<const v8bf*>(&sA[wm*64 + i*16 + (l&15)][ks*32 + (l>>4)*8]);
        bfr[i] = *reinterpret_cast<const v8bf*>(&sB[wn*64 + i*16 + (l&15)][ks*32 + (l>>4)*8]);
      }
      #pragma unroll
      for (int mi = 0; mi < 4; mi++)
        #pragma unroll
        for (int ni = 0; ni < 4; ni++)
          acc[mi][ni] = mfma16(af[mi], bfr[ni], acc[mi][ni]);
    }
    __syncthreads();
  }
  float scale = (z == 0) ? 0.125f : 1.0f;
  #pragma unroll
  for (int mi = 0; mi < 4; mi++){
    int row = m0 + wm*64 + mi*16 + (l>>4)*4;
    #pragma unroll
    for (int ni = 0; ni < 4; ni++){
      int col = n0 + wn*64 + ni*16 + (l&15);
      float bc = bias[col];
      #pragma unroll
      for (int jj = 0; jj < 4; jj++)
        out[(row+jj)*TD + col] = f2bf((acc[mi][ni][jj] + bc) * scale);
    }
  }
}

// ---------------- qg projection: tokens[GPOS] @ Wqg + bqg, *0.125 ----------------
__global__ void qg_proj(const short* __restrict__ tokens, const float* __restrict__ Wqg,
                        const float* __restrict__ bqg, short* __restrict__ qg){
  int b = blockIdx.x, h = blockIdx.y;
  int t = threadIdx.x;
  int q = t >> 2, d0 = (t & 3) * 16;
  float acc[16] = {};
  if (q < G_){
    int n = gpos(q);
    const short* tok = tokens + (b*N_ + n)*TD;
    for (int kk = 0; kk < TD; kk++){
      float tv = bf2f(tok[kk]);
      const float* wr = Wqg + kk*TD + h*64 + d0;
      #pragma unroll
      for (int e = 0; e < 16; e++) acc[e] += tv * wr[e];
    }
    #pragma unroll
    for (int e = 0; e < 16; e++) acc[e] = (acc[e] + bqg[h*64 + d0 + e]) * 0.125f;
  }
  short* o = qg + (b*64 + q)*TD + h*64 + d0;
  #pragma unroll
  for (int e = 0; e < 16; e++) o[e] = f2bf(acc[e]);
}

// ---------------- transpose v,vga -> per-head [B*H][64][N] -----------------------
__global__ __launch_bounds__(256) void transpose_v(const short* __restrict__ vbuf,
                                                   const short* __restrict__ vgabuf,
                                                   short* __restrict__ vT, short* __restrict__ vgaT){
  __shared__ short sT[64][264];
  int which = blockIdx.z;
  const short* src = which ? vgabuf : vbuf;
  short* dst = which ? vgaT : vT;
  int bh = blockIdx.y; int b = bh / H_, h = bh % H_;
  int n0 = blockIdx.x * 256;
  int t = threadIdx.x;
  #pragma unroll
  for (int p = 0; p < 8; p++){
    int nl = p*32 + (t >> 3);
    int d0 = (t & 7) * 8;
    short v[8];
    *reinterpret_cast<int4v*>(v) = *reinterpret_cast<const int4v*>(src + (b*N_ + n0 + nl)*TD + h*64 + d0);
    #pragma unroll
    for (int e = 0; e < 8; e++) sT[d0+e][nl] = v[e];
  }
  __syncthreads();
  #pragma unroll
  for (int e = 0; e < 8; e++){
    int w16 = t*8 + e;
    int d = w16 >> 5, nc = (w16 & 31) * 8;
    int4v val = *reinterpret_cast<const int4v*>(&sT[d][nc]);
    *reinterpret_cast<int4v*>(dst + (bh*64 + d)*N_ + n0 + nc) = val;
  }
}

// ---------------- band + global-key attention (flash-style) ----------------------
__global__ __launch_bounds__(256) void band_attn(
    const short* __restrict__ qb, const short* __restrict__ kbuf, const short* __restrict__ vT,
    float* __restrict__ out)
{
  __shared__ short sK[384][72];
  __shared__ short sKg[64][72];
  __shared__ short sVT[64][392];
  __shared__ short sVgT[64][72];
  __shared__ short sP[4][32][40];
  int c = blockIdx.x;
  int bh = blockIdx.y; int b = bh / H_, h = bh % H_;
  int tid = threadIdx.x, l = tid & 63, w = tid >> 6;

  for (int i = 0; i < 12; i++){
    int ch = i*256 + tid;
    { // sK: band keys, 384 rows x 64 d
      int j = ch >> 3, cb = (ch & 7) * 8;
      int ka = c*128 - 128 + j;
      int4v val = {};
      if (ka >= 0 && ka < N_)
        val = *reinterpret_cast<const int4v*>(kbuf + (b*N_ + ka)*TD + h*64 + cb);
      *reinterpret_cast<int4v*>(&sK[j][cb]) = val;
    }
    { // sVT: 64 d x 384 keys (from per-head transposed V)
      int d = ch / 48, jc = (ch % 48) * 8;
      int ka = c*128 - 128 + jc;
      int4v val = {};
      if (ka >= 0 && ka + 7 < N_)
        val = *reinterpret_cast<const int4v*>(vT + (bh*64 + d)*N_ + ka);
      *reinterpret_cast<int4v*>(&sVT[d][jc]) = val;
    }
  }
  { // sKg: 50 global keys (pad to 64)
    int ch = tid;
    #pragma unroll
    for (int i = 0; i < 2; i++, ch += 256){
      int g = ch >> 3, cb = (ch & 7) * 8;
      int4v val = {};
      if (g < G_)
        val = *reinterpret_cast<const int4v*>(kbuf + (b*N_ + gpos(g))*TD + h*64 + cb);
      *reinterpret_cast<int4v*>(&sKg[g][cb]) = val;
    }
  }
  for (int i = 0; i < 16; i++){ // sVgT: 64 d x 64 keys (scalar gather)
    int idx = i*256 + tid;
    int d = idx >> 6, g = idx & 63;
    short val = 0;
    if (g < G_) val = vT[(bh*64 + d)*N_ + gpos(g)];
    sVgT[d][g] = val;
  }
  __syncthreads();

  int qrow0 = c*128 + w*32;
  v8bf aq[2][2];
  #pragma unroll
  for (int r = 0; r < 2; r++)
    #pragma unroll
    for (int s = 0; s < 2; s++)
      aq[r][s] = *reinterpret_cast<const v8bf*>(qb + (b*N_ + qrow0 + r*16 + (l&15))*TD + h*64 + s*32 + (l>>4)*8);

  f32x4 o[2][4] = {};
  float mrun[2][4], lrun[2][4];
  #pragma unroll
  for (int r = 0; r < 2; r++)
    #pragma unroll
    for (int jj = 0; jj < 4; jj++){ mrun[r][jj] = -1e30f; lrun[r][jj] = 0.f; }

  for (int kb2 = 0; kb2 < 14; kb2++){
    bool isg = kb2 < 2;
    int key0 = isg ? kb2*32 : (kb2 - 2)*32;
    v8bf bkf[2][2];
    #pragma unroll
    for (int kc = 0; kc < 2; kc++)
      #pragma unroll
      for (int s = 0; s < 2; s++){
        int krow = key0 + kc*16 + (l & 15);
        bkf[kc][s] = isg ? *reinterpret_cast<const v8bf*>(&sKg[krow][s*32 + (l>>4)*8])
                         : *reinterpret_cast<const v8bf*>(&sK [krow][s*32 + (l>>4)*8]);
      }
    #pragma unroll
    for (int r = 0; r < 2; r++){
      f32x4 sc0 = {}, sc1 = {};
      sc0 = mfma16(aq[r][0], bkf[0][0], sc0);
      sc0 = mfma16(aq[r][1], bkf[0][1], sc0);
      sc1 = mfma16(aq[r][0], bkf[1][0], sc1);
      sc1 = mfma16(aq[r][1], bkf[1][1], sc1);
      int irow_base = w*32 + r*16 + (l>>4)*4;
      #pragma unroll
      for (int jj = 0; jj < 4; jj++){
        if (isg){
          int key = key0 + (l & 15);
          if (key        >= G_) sc0[jj] = -1e30f;
          if (key + 16   >= G_) sc1[jj] = -1e30f;
        } else {
          int i_ = irow_base + jj;
          #pragma unroll
          for (int kc = 0; kc < 2; kc++){
            int j_ = key0 + kc*16 + (l & 15);
            int rel = j_ - 128 - i_;
            int absk = c*128 + j_ - 128;
            bool valid = (rel >= -128) && (rel <= 128) && (absk >= 0) && (absk < N_);
            if (!valid){ if (kc == 0) sc0[jj] = -1e30f; else sc1[jj] = -1e30f; }
          }
        }
      }
      #pragma unroll
      for (int jj = 0; jj < 4; jj++){
        float v_ = fmaxf(sc0[jj], sc1[jj]);
        #pragma unroll
        for (int off = 1; off < 16; off <<= 1) v_ = fmaxf(v_, __shfl_xor(v_, off, 64));
        float mnew = fmaxf(mrun[r][jj], v_);
        float p0 = __expf(sc0[jj] - mnew), p1 = __expf(sc1[jj] - mnew);
        float s_ = p0 + p1;
        #pragma unroll
        for (int off = 1; off < 16; off <<= 1) s_ += __shfl_xor(s_, off, 64);
        float f_ = __expf(mrun[r][jj] - mnew);
        lrun[r][jj] = lrun[r][jj]*f_ + s_;
        mrun[r][jj] = mnew;
        #pragma unroll
        for (int cf = 0; cf < 4; cf++) o[r][cf][jj] *= f_;
        int prow = r*16 + (l>>4)*4 + jj;
        sP[w][prow][(l & 15)]      = f2bf(p0);
        sP[w][prow][16 + (l & 15)] = f2bf(p1);
      }
    }
    v8bf ap[2];
    #pragma unroll
    for (int r = 0; r < 2; r++)
      ap[r] = *reinterpret_cast<const v8bf*>(&sP[w][r*16 + (l&15)][(l>>4)*8]);
    #pragma unroll
    for (int cf = 0; cf < 4; cf++){
      v8bf bv = isg ? *reinterpret_cast<const v8bf*>(&sVgT[cf*16 + (l&15)][key0 + (l>>4)*8])
                    : *reinterpret_cast<const v8bf*>(&sVT [cf*16 + (l&15)][key0 + (l>>4)*8]);
      #pragma unroll
      for (int r = 0; r < 2; r++) o[r][cf] = mfma16(ap[r], bv, o[r][cf]);
    }
  }
  #pragma unroll
  for (int r = 0; r < 2; r++)
    #pragma unroll
    for (int jj = 0; jj < 4; jj++){
      float inv = 1.0f / lrun[r][jj];
      int n = c*128 + w*32 + r*16 + (l>>4)*4 + jj;
      int i0 = (n >> 7)*2, j0 = (n & 127)*2;
      #pragma unroll
      for (int cf = 0; cf < 4; cf++){
        float val = o[r][cf][jj] * inv;
        int t_ = h*64 + cf*16 + (l & 15);
        int cc = t_ >> 2, wi = (t_ >> 1) & 1, wj = t_ & 1;
        out[((b*C_ + cc)*IMG + i0 + wi)*IMG + j0 + wj] = val;
      }
    }
}

// ---------------- global-token attention: split-K flash partials -----------------
__global__ __launch_bounds__(256) void gattn_partial(
    const short* __restrict__ qgb, const short* __restrict__ kga, const short* __restrict__ vgaT,
    float* __restrict__ gpart)
{
  __shared__ short sP[4][64][40];
  int bh = blockIdx.x; int b = bh / H_, h = bh % H_;
  int kc = blockIdx.y;
  int tid = threadIdx.x, l = tid & 63, w = tid >> 6;
  v8bf aq[4][2];
  #pragma unroll
  for (int rf = 0; rf < 4; rf++)
    #pragma unroll
    for (int s = 0; s < 2; s++)
      aq[rf][s] = *reinterpret_cast<const v8bf*>(qgb + (b*64 + rf*16 + (l&15))*TD + h*64 + s*32 + (l>>4)*8);
  f32x4 o[4][4] = {};
  float mrun[4][4], lrun[4][4];
  #pragma unroll
  for (int rf = 0; rf < 4; rf++)
    #pragma unroll
    for (int jj = 0; jj < 4; jj++){ mrun[rf][jj] = -1e30f; lrun[rf][jj] = 0.f; }
  int keybase = kc*1024 + w*256;
  for (int st = 0; st < 8; st++){
    int key0 = keybase + st*32;
    v8bf bkf[2][2];
    #pragma unroll
    for (int kc2 = 0; kc2 < 2; kc2++)
      #pragma unroll
      for (int s = 0; s < 2; s++)
        bkf[kc2][s] = *reinterpret_cast<const v8bf*>(kga + (b*N_ + key0 + kc2*16 + (l&15))*TD + h*64 + s*32 + (l>>4)*8);
    #pragma unroll
    for (int rf = 0; rf < 4; rf++){
      f32x4 sc0 = {}, sc1 = {};
      sc0 = mfma16(aq[rf][0], bkf[0][0], sc0);
      sc0 = mfma16(aq[rf][1], bkf[0][1], sc0);
      sc1 = mfma16(aq[rf][0], bkf[1][0], sc1);
      sc1 = mfma16(aq[rf][1], bkf[1][1], sc1);
      #pragma unroll
      for (int jj = 0; jj < 4; jj++){
        float v_ = fmaxf(sc0[jj], sc1[jj]);
        #pragma unroll
        for (int off = 1; off < 16; off <<= 1) v_ = fmaxf(v_, __shfl_xor(v_, off, 64));
        float mnew = fmaxf(mrun[rf][jj], v_);
        float p0 = __expf(sc0[jj] - mnew), p1 = __expf(sc1[jj] - mnew);
        float s_ = p0 + p1;
        #pragma unroll
        for (int off = 1; off < 16; off <<= 1) s_ += __shfl_xor(s_, off, 64);
        float f_ = __expf(mrun[rf][jj] - mnew);
        lrun[rf][jj] = lrun[rf][jj]*f_ + s_;
        mrun[rf][jj] = mnew;
        #pragma unroll
        for (int cf = 0; cf < 4; cf++) o[rf][cf][jj] *= f_;
        int prow = rf*16 + (l>>4)*4 + jj;
        sP[w][prow][(l & 15)]      = f2bf(p0);
        sP[w][prow][16 + (l & 15)] = f2bf(p1);
      }
    }
    v8bf ap[4];
    #pragma unroll
    for (int rf = 0; rf < 4; rf++)
      ap[rf] = *reinterpret_cast<const v8bf*>(&sP[w][rf*16 + (l&15)][(l>>4)*8]);
    #pragma unroll
    for (int cf = 0; cf < 4; cf++){
      v8bf bv = *reinterpret_cast<const v8bf*>(vgaT + (bh*64 + cf*16 + (l&15))*N_ + key0 + (l>>4)*8);
      #pragma unroll
      for (int rf = 0; rf < 4; rf++) o[rf][cf] = mfma16(ap[rf], bv, o[rf][cf]);
    }
  }
  float* base = gpart + (size_t)((bh*16 + kc)*4 + w) * 4224;
  #pragma unroll
  for (int rf = 0; rf < 4; rf++)
    #pragma unroll
    for (int jj = 0; jj < 4; jj++){
      int q = rf*16 + (l>>4)*4 + jj;
      if ((l & 15) == 0){ base[q] = mrun[rf][jj]; base[64 + q] = lrun[rf][jj]; }
      #pragma unroll
      for (int cf = 0; cf < 4; cf++)
        base[128 + q*64 + cf*16 + (l & 15)] = o[rf][cf][jj];
    }
}

// ---------------- combine partials, write GPOS rows ------------------------------
__global__ void gattn_combine(const float* __restrict__ gpart, float* __restrict__ out){
  int bh = blockIdx.x; int b = bh / H_, h = bh % H_;
  int t = threadIdx.x;
  int q = t >> 2, d0 = (t & 3) * 16;
  if (q >= G_) return;
  const float* pb = gpart + (size_t)bh * 64 * 4224;
  float M = -1e30f;
  for (int p = 0; p < 64; p++) M = fmaxf(M, pb[p*4224 + q]);
  float L = 0.f; float acc[16] = {};
  for (int p = 0; p < 64; p++){
    const float* pp = pb + p*4224;
    float wgt = __expf(pp[q] - M);
    L += pp[64 + q] * wgt;
    #pragma unroll
    for (int e = 0; e < 16; e++) acc[e] += pp[128 + q*64 + d0 + e] * wgt;
  }
  float invL = 1.0f / L;
  int n = gpos(q);
  int i0 = (n >> 7)*2, j0 = (n & 127)*2;
  #pragma unroll
  for (int e = 0; e < 16; e++){
    int t_ = h*64 + d0 + e;
    int cc = t_ >> 2, wi = (t_ >> 1) & 1, wj = t_ & 1;
    out[((b*C_ + cc)*IMG + i0 + wi)*IMG + j0 + wj] = acc[e] * invL;
  }
}

extern "C" void kernel_launch(void* const* d_in, const int* in_sizes, int n_in,
                              void* d_out, int out_size, void* d_ws, size_t ws_size,
                              hipStream_t stream)
{
  (void)in_sizes; (void)n_in; (void)out_size; (void)ws_size;
  const float* x   = (const float*)d_in[0];
  const float* Wq  = (const float*)d_in[1];  const float* bq  = (const float*)d_in[2];
  const float* Wk  = (const float*)d_in[3];  const float* bk  = (const float*)d_in[4];
  const float* Wv  = (const float*)d_in[5];  const float* bv  = (const float*)d_in[6];
  const float* Wqg = (const float*)d_in[7];  const float* bqg = (const float*)d_in[8];
  const float* Wkg = (const float*)d_in[9];  const float* bkg = (const float*)d_in[10];
  const float* Wvg = (const float*)d_in[11]; const float* bvg = (const float*)d_in[12];
  float* out = (float*)d_out;

  short* ws = (short*)d_ws;
  const size_t SZ = (size_t)B_ * N_ * TD;     // 12,582,912
  short* tokens  = ws;
  short* Wt      = tokens  + SZ;
  short* qbuf    = Wt      + (size_t)5*TD*TD;
  short* kbuf    = qbuf    + SZ;
  short* vbuf    = kbuf    + SZ;
  short* kgabuf  = vbuf    + SZ;
  short* vgabuf  = kgabuf  + SZ;
  short* vT      = vgabuf  + SZ;
  short* vgaT    = vT      + SZ;
  short* qgb     = vgaT    + SZ;
  float* gpart   = (float*)(qgb + (size_t)B_*64*TD);

  prep_w<<<dim3(576,5), dim3(256), 0, stream>>>(Wq, Wk, Wv, Wkg, Wvg, Wt);
  tokenize<<<dim3(6144), dim3(256), 0, stream>>>(x, tokens);
  gemm_proj<<<dim3(256,3,5), dim3(256), 0, stream>>>(tokens, Wt, bq, bk, bv, bkg, bvg,
                                                     qbuf, kbuf, vbuf, kgabuf, vgabuf);
  qg_proj<<<dim3(2,6), dim3(256), 0, stream>>>(tokens, Wqg, bqg, qgb);
  transpose_v<<<dim3(64,12,2), dim3(256), 0, stream>>>(vbuf, vgabuf, vT, vgaT);
  band_attn<<<dim3(128,12), dim3(256), 0, stream>>>(qbuf, kbuf, vT, out);
  gattn_partial<<<dim3(12,16), dim3(256), 0, stream>>>(qgb, kgabuf, vgaT, gpart);
  gattn_combine<<<dim3(12), dim3(256), 0, stream>>>(gpart, out);
}

// Round 2
// 378.953 us; speedup vs baseline: 1.4715x; 1.4715x over previous
//
#include <hip/hip_runtime.h>

#define DEVI __device__ __forceinline__

typedef __bf16 v8bf __attribute__((ext_vector_type(8)));
typedef float f32x4 __attribute__((ext_vector_type(4)));
typedef int int4v __attribute__((ext_vector_type(4)));

constexpr int B_  = 2;
constexpr int C_  = 96;
constexpr int IMG = 256;
constexpr int N_  = 16384;   // tokens
constexpr int TD  = 384;
constexpr int H_  = 6;
constexpr int G_  = 50;

DEVI short f2bf(float f){
  unsigned u = __builtin_bit_cast(unsigned, f);
  u = (u + 0x7fffu + ((u >> 16) & 1u)) >> 16;
  return (short)u;
}
DEVI int gpos(int g){ return (16383 * g) / 49; }   // np.linspace(0,16383,50).astype(int32)

DEVI f32x4 mfma16(v8bf a, v8bf b, f32x4 c){
  return __builtin_amdgcn_mfma_f32_16x16x32_bf16(a, b, c, 0, 0, 0);
}

// ---------------- prep: W (k-major f32) -> Wt (n-major bf16), 6 weights ----------
__global__ void prep_w(const float* __restrict__ w0, const float* __restrict__ w1,
                       const float* __restrict__ w2, const float* __restrict__ w3,
                       const float* __restrict__ w4, const float* __restrict__ w5,
                       short* __restrict__ Wt){
  int z = blockIdx.y;
  const float* W = z==0 ? w0 : z==1 ? w1 : z==2 ? w2 : z==3 ? w3 : z==4 ? w4 : w5;
  int idx = blockIdx.x * 256 + threadIdx.x;      // idx = n*384 + k
  int n = idx / TD, k = idx % TD;
  Wt[z*TD*TD + idx] = f2bf(W[k*TD + n]);
}

// ---------------- tokenize: x f32 -> tokens bf16 (B,N,TD) ------------------------
__global__ void tokenize(const float* __restrict__ x, short* __restrict__ tokens){
  int idx = blockIdx.x * 256 + threadIdx.x;
  int t8 = idx % (TD/8);
  int bn = idx / (TD/8);
  int n = bn % N_, b = bn / N_;
  int t0 = t8 * 8;
  int i0 = (n >> 7) * 2, j0 = (n & 127) * 2;
  short o[8];
  #pragma unroll
  for (int e = 0; e < 8; e++){
    int t = t0 + e;
    int c = t >> 2, wi = (t >> 1) & 1, wj = t & 1;
    o[e] = f2bf(x[((b*C_ + c)*IMG + i0 + wi)*IMG + j0 + wj]);
  }
  *reinterpret_cast<int4v*>(tokens + bn*TD + t0) = *reinterpret_cast<int4v*>(o);
}

// ---------------- gather global-token rows for qg GEMM ---------------------------
__global__ void gather_tokg(const short* __restrict__ tokens, short* __restrict__ tokg){
  int idx = blockIdx.x*256 + threadIdx.x;        // 24 blocks -> 6144 chunks
  int r = idx / 48, cb = (idx % 48)*8;
  int b = r >> 6, q = r & 63;
  int4v val = {};
  if (q < G_) val = *reinterpret_cast<const int4v*>(tokens + ((size_t)b*N_ + gpos(q))*TD + cb);
  *reinterpret_cast<int4v*>(tokg + r*TD + cb) = val;
}

// ---------------- 5-way projection GEMM ------------------------------------------
__global__ __launch_bounds__(256) void gemm_proj(
    const short* __restrict__ A, const short* __restrict__ Wt,
    const float* __restrict__ bq, const float* __restrict__ bk, const float* __restrict__ bv,
    const float* __restrict__ bkg, const float* __restrict__ bvg,
    short* __restrict__ qbuf, short* __restrict__ kbuf, short* __restrict__ vbuf,
    short* __restrict__ kgabuf, short* __restrict__ vgabuf)
{
  __shared__ short sA[128][72];
  __shared__ short sB[128][72];
  int z = blockIdx.z;
  const float* bias = z==0 ? bq : z==1 ? bk : z==2 ? bv : z==3 ? bkg : bvg;
  short* out = z==0 ? qbuf : z==1 ? kbuf : z==2 ? vbuf : z==3 ? kgabuf : vgabuf;
  const short* Wz = Wt + z*TD*TD;
  int m0 = blockIdx.x * 128, n0 = blockIdx.y * 128;
  int tid = threadIdx.x, l = tid & 63, w = tid >> 6;
  int wm = w >> 1, wn = w & 1;
  f32x4 acc[4][4] = {};
  for (int k0 = 0; k0 < TD; k0 += 64){
    #pragma unroll
    for (int i = 0; i < 4; i++){
      int ch = i*256 + tid; int row = ch >> 3, cb = (ch & 7) * 8;
      int4v va = *reinterpret_cast<const int4v*>(A  + (m0+row)*TD + k0 + cb);
      int4v vb = *reinterpret_cast<const int4v*>(Wz + (n0+row)*TD + k0 + cb);
      *reinterpret_cast<int4v*>(&sA[row][cb]) = va;
      *reinterpret_cast<int4v*>(&sB[row][cb]) = vb;
    }
    __syncthreads();
    #pragma unroll
    for (int ks = 0; ks < 2; ks++){
      v8bf af[4], bfr[4];
      #pragma unroll
      for (int i = 0; i < 4; i++){
        af[i]  = *reinterpret_cast<const v8bf*>(&sA[wm*64 + i*16 + (l&15)][ks*32 + (l>>4)*8]);
        bfr[i] = *reinterpret_cast<const v8bf*>(&sB[wn*64 + i*16 + (l&15)][ks*32 + (l>>4)*8]);
      }
      #pragma unroll
      for (int mi = 0; mi < 4; mi++)
        #pragma unroll
        for (int ni = 0; ni < 4; ni++)
          acc[mi][ni] = mfma16(af[mi], bfr[ni], acc[mi][ni]);
    }
    __syncthreads();
  }
  float scale = (z == 0) ? 0.125f : 1.0f;
  #pragma unroll
  for (int mi = 0; mi < 4; mi++){
    int row = m0 + wm*64 + mi*16 + (l>>4)*4;
    #pragma unroll
    for (int ni = 0; ni < 4; ni++){
      int col = n0 + wn*64 + ni*16 + (l&15);
      float bc = bias[col];
      #pragma unroll
      for (int jj = 0; jj < 4; jj++)
        out[(row+jj)*TD + col] = f2bf((acc[mi][ni][jj] + bc) * scale);
    }
  }
}

// ---------------- qg GEMM: tokg(128x384) @ Wqg + bqg, *0.125 ---------------------
__global__ __launch_bounds__(256) void gemm_qg(
    const short* __restrict__ A, const short* __restrict__ Wt,
    const float* __restrict__ bias, short* __restrict__ out)
{
  __shared__ short sA[128][72];
  __shared__ short sB[128][72];
  const short* Wz = Wt + 5*TD*TD;
  int n0 = blockIdx.x * 128;
  int tid = threadIdx.x, l = tid & 63, w = tid >> 6;
  int wm = w >> 1, wn = w & 1;
  f32x4 acc[4][4] = {};
  for (int k0 = 0; k0 < TD; k0 += 64){
    #pragma unroll
    for (int i = 0; i < 4; i++){
      int ch = i*256 + tid; int row = ch >> 3, cb = (ch & 7) * 8;
      *reinterpret_cast<int4v*>(&sA[row][cb]) = *reinterpret_cast<const int4v*>(A  + row*TD + k0 + cb);
      *reinterpret_cast<int4v*>(&sB[row][cb]) = *reinterpret_cast<const int4v*>(Wz + (n0+row)*TD + k0 + cb);
    }
    __syncthreads();
    #pragma unroll
    for (int ks = 0; ks < 2; ks++){
      v8bf af[4], bfr[4];
      #pragma unroll
      for (int i = 0; i < 4; i++){
        af[i]  = *reinterpret_cast<const v8bf*>(&sA[wm*64 + i*16 + (l&15)][ks*32 + (l>>4)*8]);
        bfr[i] = *reinterpret_cast<const v8bf*>(&sB[wn*64 + i*16 + (l&15)][ks*32 + (l>>4)*8]);
      }
      #pragma unroll
      for (int mi = 0; mi < 4; mi++)
        #pragma unroll
        for (int ni = 0; ni < 4; ni++)
          acc[mi][ni] = mfma16(af[mi], bfr[ni], acc[mi][ni]);
    }
    __syncthreads();
  }
  #pragma unroll
  for (int mi = 0; mi < 4; mi++){
    int row = wm*64 + mi*16 + (l>>4)*4;
    #pragma unroll
    for (int ni = 0; ni < 4; ni++){
      int col = n0 + wn*64 + ni*16 + (l&15);
      float bc = bias[col];
      #pragma unroll
      for (int jj = 0; jj < 4; jj++)
        out[(row+jj)*TD + col] = f2bf((acc[mi][ni][jj] + bc) * 0.125f);
    }
  }
}

// ---------------- transpose v,vga -> per-head [B*H][64][N] -----------------------
__global__ __launch_bounds__(256) void transpose_v(const short* __restrict__ vbuf,
                                                   const short* __restrict__ vgabuf,
                                                   short* __restrict__ vT, short* __restrict__ vgaT){
  __shared__ short sT[64][264];
  int which = blockIdx.z;
  const short* src = which ? vgabuf : vbuf;
  short* dst = which ? vgaT : vT;
  int bh = blockIdx.y; int b = bh / H_, h = bh % H_;
  int n0 = blockIdx.x * 256;
  int t = threadIdx.x;
  #pragma unroll
  for (int p = 0; p < 8; p++){
    int nl = p*32 + (t >> 3);
    int d0 = (t & 7) * 8;
    short v[8];
    *reinterpret_cast<int4v*>(v) = *reinterpret_cast<const int4v*>(src + (b*N_ + n0 + nl)*TD + h*64 + d0);
    #pragma unroll
    for (int e = 0; e < 8; e++) sT[d0+e][nl] = v[e];
  }
  __syncthreads();
  #pragma unroll
  for (int e = 0; e < 8; e++){
    int w16 = t*8 + e;
    int d = w16 >> 5, nc = (w16 & 31) * 8;
    int4v val = *reinterpret_cast<const int4v*>(&sT[d][nc]);
    *reinterpret_cast<int4v*>(dst + ((size_t)bh*64 + d)*N_ + n0 + nc) = val;
  }
}

// ---------------- band + global-key attention (8 waves, 64-key steps) ------------
__global__ __launch_bounds__(512) void band_attn(
    const short* __restrict__ qb, const short* __restrict__ kbuf, const short* __restrict__ vT,
    float* __restrict__ out)
{
  __shared__ short sKV[448][72];   // rows 0..63 global keys, 64..447 band keys
  __shared__ short sVT[64][456];   // cols 0..63 global V, 64..447 band V
  __shared__ short sP[8][16][72];
  int c = blockIdx.x;
  int bh = blockIdx.y; int b = bh / H_, h = bh % H_;
  int tid = threadIdx.x, l = tid & 63, w = tid >> 6;
  int cb0 = c*128 - 128;

  #pragma unroll
  for (int it = 0; it < 6; it++){               // band K
    int ch = it*512 + tid;
    int j = ch >> 3, cbk = (ch & 7)*8;
    int ka = cb0 + j;
    int4v val = {};
    if (ka >= 0 && ka < N_) val = *reinterpret_cast<const int4v*>(kbuf + (b*N_+ka)*TD + h*64 + cbk);
    *reinterpret_cast<int4v*>(&sKV[64+j][cbk]) = val;
  }
  {                                             // global K (50 of 64)
    int g = tid >> 3, cbk = (tid & 7)*8;
    int4v val = {};
    if (g < G_) val = *reinterpret_cast<const int4v*>(kbuf + (b*N_+gpos(g))*TD + h*64 + cbk);
    *reinterpret_cast<int4v*>(&sKV[g][cbk]) = val;
  }
  #pragma unroll
  for (int it = 0; it < 6; it++){               // band V^T
    int ch = it*512 + tid;
    int d = ch / 48, jc = (ch % 48)*8;
    int ka = cb0 + jc;
    int4v val = {};
    if (ka >= 0 && ka <= N_-8) val = *reinterpret_cast<const int4v*>(vT + ((size_t)bh*64+d)*N_ + ka);
    *reinterpret_cast<int4v*>(&sVT[d][64+jc]) = val;
  }
  #pragma unroll
  for (int it = 0; it < 8; it++){               // global V^T (scalar gather)
    int ch = it*512 + tid;
    int d = ch >> 6, g = ch & 63;
    short val = 0;
    if (g < G_) val = vT[((size_t)bh*64+d)*N_ + gpos(g)];
    sVT[d][g] = val;
  }

  int qrow0 = c*128 + w*16;
  v8bf aq[2];
  #pragma unroll
  for (int s = 0; s < 2; s++)
    aq[s] = *reinterpret_cast<const v8bf*>(qb + (b*N_ + qrow0 + (l&15))*TD + h*64 + s*32 + (l>>4)*8);

  __syncthreads();

  f32x4 o[4] = {};
  float mrun[4], lrun[4];
  #pragma unroll
  for (int jj = 0; jj < 4; jj++){ mrun[jj] = -1e30f; lrun[jj] = 0.f; }

  for (int step = 0; step < 7; step++){
    int key0 = step*64;
    v8bf bkf[4][2];
    #pragma unroll
    for (int kc = 0; kc < 4; kc++)
      #pragma unroll
      for (int s = 0; s < 2; s++)
        bkf[kc][s] = *reinterpret_cast<const v8bf*>(&sKV[key0 + kc*16 + (l&15)][s*32 + (l>>4)*8]);
    f32x4 sc[4] = {};
    #pragma unroll
    for (int kc = 0; kc < 4; kc++){
      sc[kc] = mfma16(aq[0], bkf[kc][0], sc[kc]);
      sc[kc] = mfma16(aq[1], bkf[kc][1], sc[kc]);
    }
    // masking
    if (step == 0){
      if (48 + (l & 15) >= G_){
        #pragma unroll
        for (int jj = 0; jj < 4; jj++) sc[3][jj] = -1e30f;
      }
    } else {
      int s0 = key0 - 64;
      bool allvalid = (s0 >= w*16 + 15) && (s0 + 63 <= 256 + w*16)
                   && (cb0 + s0 >= 0) && (cb0 + s0 + 63 < N_);
      if (!allvalid){
        #pragma unroll
        for (int kc = 0; kc < 4; kc++){
          int j_ = s0 + kc*16 + (l & 15);
          int absk = cb0 + j_;
          bool okk = (absk >= 0) && (absk < N_);
          #pragma unroll
          for (int jj = 0; jj < 4; jj++){
            int il = w*16 + (l>>4)*4 + jj;
            int rel = j_ - 128 - il;
            if (!okk || rel < -128 || rel > 128) sc[kc][jj] = -1e30f;
          }
        }
      }
    }
    // online softmax (wave-parallel, 4 independent jj chains)
    #pragma unroll
    for (int jj = 0; jj < 4; jj++){
      float mk = fmaxf(fmaxf(sc[0][jj], sc[1][jj]), fmaxf(sc[2][jj], sc[3][jj]));
      #pragma unroll
      for (int off = 1; off < 16; off <<= 1) mk = fmaxf(mk, __shfl_xor(mk, off, 64));
      float mnew = fmaxf(mrun[jj], mk);
      float f_ = __expf(mrun[jj] - mnew);
      mrun[jj] = mnew;
      float p0 = __expf(sc[0][jj]-mnew), p1 = __expf(sc[1][jj]-mnew);
      float p2 = __expf(sc[2][jj]-mnew), p3 = __expf(sc[3][jj]-mnew);
      float s_ = (p0+p1)+(p2+p3);
      #pragma unroll
      for (int off = 1; off < 16; off <<= 1) s_ += __shfl_xor(s_, off, 64);
      lrun[jj] = lrun[jj]*f_ + s_;
      #pragma unroll
      for (int cf = 0; cf < 4; cf++) o[cf][jj] *= f_;
      int pr = (l>>4)*4 + jj;
      sP[w][pr][(l&15)]    = f2bf(p0);
      sP[w][pr][16+(l&15)] = f2bf(p1);
      sP[w][pr][32+(l&15)] = f2bf(p2);
      sP[w][pr][48+(l&15)] = f2bf(p3);
    }
    // PV
    v8bf ap[2];
    #pragma unroll
    for (int s2 = 0; s2 < 2; s2++)
      ap[s2] = *reinterpret_cast<const v8bf*>(&sP[w][(l&15)][s2*32 + (l>>4)*8]);
    #pragma unroll
    for (int cf = 0; cf < 4; cf++){
      #pragma unroll
      for (int s2 = 0; s2 < 2; s2++){
        v8bf bv = *reinterpret_cast<const v8bf*>(&sVT[cf*16 + (l&15)][key0 + s2*32 + (l>>4)*8]);
        o[cf] = mfma16(ap[s2], bv, o[cf]);
      }
    }
  }
  #pragma unroll
  for (int jj = 0; jj < 4; jj++){
    float inv = 1.0f / lrun[jj];
    int n = c*128 + w*16 + (l>>4)*4 + jj;
    int i0 = (n >> 7)*2, j0 = (n & 127)*2;
    #pragma unroll
    for (int cf = 0; cf < 4; cf++){
      float val = o[cf][jj] * inv;
      int t_ = h*64 + cf*16 + (l & 15);
      int cc = t_ >> 2, wi = (t_ >> 1) & 1, wj = t_ & 1;
      out[((b*C_ + cc)*IMG + i0 + wi)*IMG + j0 + wj] = val;
    }
  }
}

// ---------------- global-token attention: split-K flash partials -----------------
__global__ __launch_bounds__(256) void gattn_partial(
    const short* __restrict__ qgb, const short* __restrict__ kga, const short* __restrict__ vgaT,
    float* __restrict__ gpart)
{
  __shared__ short sP[4][64][72];
  int bh = blockIdx.x; int b = bh / H_, h = bh % H_;
  int kc = blockIdx.y;
  int tid = threadIdx.x, l = tid & 63, w = tid >> 6;
  v8bf aq[4][2];
  #pragma unroll
  for (int rf = 0; rf < 4; rf++)
    #pragma unroll
    for (int s = 0; s < 2; s++)
      aq[rf][s] = *reinterpret_cast<const v8bf*>(qgb + (b*64 + rf*16 + (l&15))*TD + h*64 + s*32 + (l>>4)*8);
  f32x4 o[4][4] = {};
  float mrun[4][4], lrun[4][4];
  #pragma unroll
  for (int rf = 0; rf < 4; rf++)
    #pragma unroll
    for (int jj = 0; jj < 4; jj++){ mrun[rf][jj] = -1e30f; lrun[rf][jj] = 0.f; }
  int keybase = kc*512 + w*128;
  for (int st = 0; st < 2; st++){
    int key0 = keybase + st*64;
    v8bf bkf[4][2];
    #pragma unroll
    for (int kc2 = 0; kc2 < 4; kc2++)
      #pragma unroll
      for (int s = 0; s < 2; s++)
        bkf[kc2][s] = *reinterpret_cast<const v8bf*>(kga + (b*N_ + key0 + kc2*16 + (l&15))*TD + h*64 + s*32 + (l>>4)*8);
    #pragma unroll
    for (int rf = 0; rf < 4; rf++){
      f32x4 sc[4] = {};
      #pragma unroll
      for (int kc2 = 0; kc2 < 4; kc2++){
        sc[kc2] = mfma16(aq[rf][0], bkf[kc2][0], sc[kc2]);
        sc[kc2] = mfma16(aq[rf][1], bkf[kc2][1], sc[kc2]);
      }
      #pragma unroll
      for (int jj = 0; jj < 4; jj++){
        float mk = fmaxf(fmaxf(sc[0][jj], sc[1][jj]), fmaxf(sc[2][jj], sc[3][jj]));
        #pragma unroll
        for (int off = 1; off < 16; off <<= 1) mk = fmaxf(mk, __shfl_xor(mk, off, 64));
        float mnew = fmaxf(mrun[rf][jj], mk);
        float f_ = __expf(mrun[rf][jj] - mnew);
        mrun[rf][jj] = mnew;
        float p0 = __expf(sc[0][jj]-mnew), p1 = __expf(sc[1][jj]-mnew);
        float p2 = __expf(sc[2][jj]-mnew), p3 = __expf(sc[3][jj]-mnew);
        float s_ = (p0+p1)+(p2+p3);
        #pragma unroll
        for (int off = 1; off < 16; off <<= 1) s_ += __shfl_xor(s_, off, 64);
        lrun[rf][jj] = lrun[rf][jj]*f_ + s_;
        #pragma unroll
        for (int cf = 0; cf < 4; cf++) o[rf][cf][jj] *= f_;
        int pr = rf*16 + (l>>4)*4 + jj;
        sP[w][pr][(l&15)]    = f2bf(p0);
        sP[w][pr][16+(l&15)] = f2bf(p1);
        sP[w][pr][32+(l&15)] = f2bf(p2);
        sP[w][pr][48+(l&15)] = f2bf(p3);
      }
    }
    #pragma unroll
    for (int cf = 0; cf < 4; cf++){
      #pragma unroll
      for (int s2 = 0; s2 < 2; s2++){
        v8bf bv = *reinterpret_cast<const v8bf*>(vgaT + ((size_t)bh*64 + cf*16 + (l&15))*N_ + key0 + s2*32 + (l>>4)*8);
        #pragma unroll
        for (int rf = 0; rf < 4; rf++){
          v8bf ap = *reinterpret_cast<const v8bf*>(&sP[w][rf*16 + (l&15)][s2*32 + (l>>4)*8]);
          o[rf][cf] = mfma16(ap, bv, o[rf][cf]);
        }
      }
    }
  }
  float* base = gpart + (size_t)((bh*32 + kc)*4 + w) * 4224;
  #pragma unroll
  for (int rf = 0; rf < 4; rf++)
    #pragma unroll
    for (int jj = 0; jj < 4; jj++){
      int q = rf*16 + (l>>4)*4 + jj;
      if ((l & 15) == 0){ base[q] = mrun[rf][jj]; base[64 + q] = lrun[rf][jj]; }
      #pragma unroll
      for (int cf = 0; cf < 4; cf++)
        base[128 + q*64 + cf*16 + (l & 15)] = o[rf][cf][jj];
    }
}

// ---------------- combine partials, write GPOS rows ------------------------------
__global__ void gattn_combine(const float* __restrict__ gpart, float* __restrict__ out){
  int bh = blockIdx.x; int b = bh / H_, h = bh % H_;
  int t = threadIdx.x;
  int q = t >> 2, d0 = (t & 3) * 16;
  if (q >= G_) return;
  const float* pb = gpart + (size_t)bh * 128 * 4224;
  float M = -1e30f;
  for (int p = 0; p < 128; p++) M = fmaxf(M, pb[p*4224 + q]);
  float L = 0.f; float acc[16] = {};
  for (int p = 0; p < 128; p++){
    const float* pp = pb + p*4224;
    float wgt = __expf(pp[q] - M);
    L += pp[64 + q] * wgt;
    #pragma unroll
    for (int e = 0; e < 16; e++) acc[e] += pp[128 + q*64 + d0 + e] * wgt;
  }
  float invL = 1.0f / L;
  int n = gpos(q);
  int i0 = (n >> 7)*2, j0 = (n & 127)*2;
  #pragma unroll
  for (int e = 0; e < 16; e++){
    int t_ = h*64 + d0 + e;
    int cc = t_ >> 2, wi = (t_ >> 1) & 1, wj = t_ & 1;
    out[((b*C_ + cc)*IMG + i0 + wi)*IMG + j0 + wj] = acc[e] * invL;
  }
}

extern "C" void kernel_launch(void* const* d_in, const int* in_sizes, int n_in,
                              void* d_out, int out_size, void* d_ws, size_t ws_size,
                              hipStream_t stream)
{
  (void)in_sizes; (void)n_in; (void)out_size; (void)ws_size;
  const float* x   = (const float*)d_in[0];
  const float* Wq  = (const float*)d_in[1];  const float* bq  = (const float*)d_in[2];
  const float* Wk  = (const float*)d_in[3];  const float* bk  = (const float*)d_in[4];
  const float* Wv  = (const float*)d_in[5];  const float* bv  = (const float*)d_in[6];
  const float* Wqg = (const float*)d_in[7];  const float* bqg = (const float*)d_in[8];
  const float* Wkg = (const float*)d_in[9];  const float* bkg = (const float*)d_in[10];
  const float* Wvg = (const float*)d_in[11]; const float* bvg = (const float*)d_in[12];
  float* out = (float*)d_out;

  short* ws = (short*)d_ws;
  const size_t SZ = (size_t)B_ * N_ * TD;     // 12,582,912 bf16
  short* tokens  = ws;
  short* Wt      = tokens  + SZ;
  short* tokg    = Wt      + (size_t)6*TD*TD;
  short* qgb     = tokg    + (size_t)128*TD;
  short* qbuf    = qgb     + (size_t)128*TD;
  short* kbuf    = qbuf    + SZ;
  short* vbuf    = kbuf    + SZ;
  short* kgabuf  = vbuf    + SZ;
  short* vgabuf  = kgabuf  + SZ;
  short* vT      = vgabuf  + SZ;
  short* vgaT    = vT      + SZ;
  // gpart (26 MB) aliases tokens+Wt: both dead once the GEMMs have run,
  // and gattn_partial launches strictly after them on the same stream.
  float* gpart   = (float*)tokens;

  prep_w<<<dim3(576,6), dim3(256), 0, stream>>>(Wq, Wk, Wv, Wkg, Wvg, Wqg, Wt);
  tokenize<<<dim3(6144), dim3(256), 0, stream>>>(x, tokens);
  gemm_proj<<<dim3(256,3,5), dim3(256), 0, stream>>>(tokens, Wt, bq, bk, bv, bkg, bvg,
                                                     qbuf, kbuf, vbuf, kgabuf, vgabuf);
  gather_tokg<<<dim3(24), dim3(256), 0, stream>>>(tokens, tokg);
  gemm_qg<<<dim3(3), dim3(256), 0, stream>>>(tokg, Wt, bqg, qgb);
  transpose_v<<<dim3(64,12,2), dim3(256), 0, stream>>>(vbuf, vgabuf, vT, vgaT);
  band_attn<<<dim3(128,12), dim3(512), 0, stream>>>(qbuf, kbuf, vT, out);
  gattn_partial<<<dim3(12,32), dim3(256), 0, stream>>>(qgb, kgabuf, vgaT, gpart);
  gattn_combine<<<dim3(12), dim3(256), 0, stream>>>(gpart, out);
}

// Round 3
// 307.100 us; speedup vs baseline: 1.8158x; 1.2340x over previous
//
#include <hip/hip_runtime.h>

#define DEVI __device__ __forceinline__

typedef __bf16 v8bf __attribute__((ext_vector_type(8)));
typedef float f32x4 __attribute__((ext_vector_type(4)));
typedef int int4v __attribute__((ext_vector_type(4)));

constexpr int B_  = 2;
constexpr int C_  = 96;
constexpr int IMG = 256;
constexpr int N_  = 16384;   // tokens
constexpr int TD  = 384;
constexpr int H_  = 6;
constexpr int G_  = 50;

DEVI short f2bf(float f){
  unsigned u = __builtin_bit_cast(unsigned, f);
  u = (u + 0x7fffu + ((u >> 16) & 1u)) >> 16;
  return (short)u;
}
DEVI int gpos(int g){ return (16383 * g) / 49; }   // np.linspace(0,16383,50).astype(int32)

DEVI f32x4 mfma16(v8bf a, v8bf b, f32x4 c){
  return __builtin_amdgcn_mfma_f32_16x16x32_bf16(a, b, c, 0, 0, 0);
}

// async global->LDS, 16B per lane; LDS dest is wave-uniform base + lane*16
DEVI void gload16(const void* g, void* l){
  __builtin_amdgcn_global_load_lds((const __attribute__((address_space(1))) void*)g,
                                   (__attribute__((address_space(3))) void*)l, 16, 0, 0);
}

// ---------------- prep: W (k-major f32) -> Wt (n-major bf16), 6 weights ----------
__global__ void prep_w(const float* __restrict__ w0, const float* __restrict__ w1,
                       const float* __restrict__ w2, const float* __restrict__ w3,
                       const float* __restrict__ w4, const float* __restrict__ w5,
                       short* __restrict__ Wt){
  int z = blockIdx.y;
  const float* W = z==0 ? w0 : z==1 ? w1 : z==2 ? w2 : z==3 ? w3 : z==4 ? w4 : w5;
  int idx = blockIdx.x * 256 + threadIdx.x;      // idx = n*384 + k
  int n = idx / TD, k = idx % TD;
  Wt[z*TD*TD + idx] = f2bf(W[k*TD + n]);
}

// ---------------- tokenize: x f32 -> tokens bf16 (B,N,TD) ------------------------
__global__ void tokenize(const float* __restrict__ x, short* __restrict__ tokens){
  int idx = blockIdx.x * 256 + threadIdx.x;
  int t8 = idx % (TD/8);
  int bn = idx / (TD/8);
  int n = bn % N_, b = bn / N_;
  int t0 = t8 * 8;
  int i0 = (n >> 7) * 2, j0 = (n & 127) * 2;
  short o[8];
  #pragma unroll
  for (int e = 0; e < 8; e++){
    int t = t0 + e;
    int c = t >> 2, wi = (t >> 1) & 1, wj = t & 1;
    o[e] = f2bf(x[((b*C_ + c)*IMG + i0 + wi)*IMG + j0 + wj]);
  }
  *reinterpret_cast<int4v*>(tokens + bn*TD + t0) = *reinterpret_cast<int4v*>(o);
}

// ---------------- gather global-token rows for qg GEMM ---------------------------
__global__ void gather_tokg(const short* __restrict__ tokens, short* __restrict__ tokg){
  int idx = blockIdx.x*256 + threadIdx.x;
  int r = idx / 48, cb = (idx % 48)*8;
  int b = r >> 6, q = r & 63;
  int4v val = {};
  if (q < G_) val = *reinterpret_cast<const int4v*>(tokens + ((size_t)b*N_ + gpos(q))*TD + cb);
  *reinterpret_cast<int4v*>(tokg + r*TD + cb) = val;
}

// ---------------- 5-way projection GEMM (m97-style: global_load_lds staging) -----
__global__ __launch_bounds__(256) void gemm_proj(
    const short* __restrict__ A, const short* __restrict__ Wt,
    const float* __restrict__ bq, const float* __restrict__ bk, const float* __restrict__ bv,
    const float* __restrict__ bkg, const float* __restrict__ bvg,
    short* __restrict__ qbuf, short* __restrict__ kbuf, short* __restrict__ vbuf,
    short* __restrict__ kgabuf, short* __restrict__ vgabuf)
{
  __shared__ short sA[128][64];
  __shared__ short sB[128][64];
  // XCD-chunked swizzle: nwg=3840, 480/XCD; adjacent ids share the B-panel on one XCD
  int lin = (blockIdx.z*3 + blockIdx.y)*256 + blockIdx.x;
  int id = (lin & 7)*480 + (lin >> 3);
  int bx = id & 255; int rest = id >> 8;
  int by = rest % 3, bz = rest / 3;
  const float* bias = bz==0 ? bq : bz==1 ? bk : bz==2 ? bv : bz==3 ? bkg : bvg;
  short* out = bz==0 ? qbuf : bz==1 ? kbuf : bz==2 ? vbuf : bz==3 ? kgabuf : vgabuf;
  const short* Wz = Wt + bz*TD*TD;
  int m0 = bx * 128, n0 = by * 128;
  int tid = threadIdx.x, l = tid & 63, w = tid >> 6;
  int wm = w >> 1, wn = w & 1;
  f32x4 acc[4][4] = {};
  for (int k0 = 0; k0 < TD; k0 += 64){
    #pragma unroll
    for (int it = 0; it < 4; it++){
      int ch = w*4 + it;
      int r = ch*8 + (l>>3), cc = (l&7)*8;
      gload16(A  + (size_t)(m0+r)*TD + k0 + cc, &sA[ch*8][0]);
      gload16(Wz + (size_t)(n0+r)*TD + k0 + cc, &sB[ch*8][0]);
    }
    __syncthreads();
    #pragma unroll
    for (int ks = 0; ks < 2; ks++){
      v8bf af[4], bfr[4];
      #pragma unroll
      for (int i = 0; i < 4; i++){
        af[i]  = *reinterpret_cast<const v8bf*>(&sA[wm*64 + i*16 + (l&15)][ks*32 + (l>>4)*8]);
        bfr[i] = *reinterpret_cast<const v8bf*>(&sB[wn*64 + i*16 + (l&15)][ks*32 + (l>>4)*8]);
      }
      #pragma unroll
      for (int mi = 0; mi < 4; mi++)
        #pragma unroll
        for (int ni = 0; ni < 4; ni++)
          acc[mi][ni] = mfma16(af[mi], bfr[ni], acc[mi][ni]);
    }
    __syncthreads();
  }
  float scale = (bz == 0) ? 0.125f : 1.0f;
  #pragma unroll
  for (int mi = 0; mi < 4; mi++){
    int row = m0 + wm*64 + mi*16 + (l>>4)*4;
    #pragma unroll
    for (int ni = 0; ni < 4; ni++){
      int col = n0 + wn*64 + ni*16 + (l&15);
      float bc = bias[col];
      #pragma unroll
      for (int jj = 0; jj < 4; jj++)
        out[(size_t)(row+jj)*TD + col] = f2bf((acc[mi][ni][jj] + bc) * scale);
    }
  }
}

// ---------------- qg GEMM: tokg(128x384) @ Wqg + bqg, *0.125 ---------------------
__global__ __launch_bounds__(256) void gemm_qg(
    const short* __restrict__ A, const short* __restrict__ Wt,
    const float* __restrict__ bias, short* __restrict__ out)
{
  __shared__ short sA[128][72];
  __shared__ short sB[128][72];
  const short* Wz = Wt + 5*TD*TD;
  int n0 = blockIdx.x * 128;
  int tid = threadIdx.x, l = tid & 63, w = tid >> 6;
  int wm = w >> 1, wn = w & 1;
  f32x4 acc[4][4] = {};
  for (int k0 = 0; k0 < TD; k0 += 64){
    #pragma unroll
    for (int i = 0; i < 4; i++){
      int ch = i*256 + tid; int row = ch >> 3, cb = (ch & 7) * 8;
      *reinterpret_cast<int4v*>(&sA[row][cb]) = *reinterpret_cast<const int4v*>(A  + row*TD + k0 + cb);
      *reinterpret_cast<int4v*>(&sB[row][cb]) = *reinterpret_cast<const int4v*>(Wz + (n0+row)*TD + k0 + cb);
    }
    __syncthreads();
    #pragma unroll
    for (int ks = 0; ks < 2; ks++){
      v8bf af[4], bfr[4];
      #pragma unroll
      for (int i = 0; i < 4; i++){
        af[i]  = *reinterpret_cast<const v8bf*>(&sA[wm*64 + i*16 + (l&15)][ks*32 + (l>>4)*8]);
        bfr[i] = *reinterpret_cast<const v8bf*>(&sB[wn*64 + i*16 + (l&15)][ks*32 + (l>>4)*8]);
      }
      #pragma unroll
      for (int mi = 0; mi < 4; mi++)
        #pragma unroll
        for (int ni = 0; ni < 4; ni++)
          acc[mi][ni] = mfma16(af[mi], bfr[ni], acc[mi][ni]);
    }
    __syncthreads();
  }
  #pragma unroll
  for (int mi = 0; mi < 4; mi++){
    int row = wm*64 + mi*16 + (l>>4)*4;
    #pragma unroll
    for (int ni = 0; ni < 4; ni++){
      int col = n0 + wn*64 + ni*16 + (l&15);
      float bc = bias[col];
      #pragma unroll
      for (int jj = 0; jj < 4; jj++)
        out[(row+jj)*TD + col] = f2bf((acc[mi][ni][jj] + bc) * 0.125f);
    }
  }
}

// ---------------- transpose v,vga -> per-head [B*H][64][N] -----------------------
__global__ __launch_bounds__(256) void transpose_v(const short* __restrict__ vbuf,
                                                   const short* __restrict__ vgabuf,
                                                   short* __restrict__ vT, short* __restrict__ vgaT){
  __shared__ short sT[64][264];
  int which = blockIdx.z;
  const short* src = which ? vgabuf : vbuf;
  short* dst = which ? vgaT : vT;
  int bh = blockIdx.y; int b = bh / H_, h = bh % H_;
  int n0 = blockIdx.x * 256;
  int t = threadIdx.x;
  #pragma unroll
  for (int p = 0; p < 8; p++){
    int nl = p*32 + (t >> 3);
    int d0 = (t & 7) * 8;
    short v[8];
    *reinterpret_cast<int4v*>(v) = *reinterpret_cast<const int4v*>(src + ((size_t)b*N_ + n0 + nl)*TD + h*64 + d0);
    #pragma unroll
    for (int e = 0; e < 8; e++) sT[d0+e][nl] = v[e];
  }
  __syncthreads();
  #pragma unroll
  for (int e = 0; e < 8; e++){
    int w16 = t*8 + e;
    int d = w16 >> 5, nc = (w16 & 31) * 8;
    int4v val = *reinterpret_cast<const int4v*>(&sT[d][nc]);
    *reinterpret_cast<int4v*>(dst + ((size_t)bh*64 + d)*N_ + n0 + nc) = val;
  }
}

// ---------------- per-bh gather of global-token K rows and V^T cols --------------
__global__ void gather_gkv(const short* __restrict__ kbuf, const short* __restrict__ vT,
                           short* __restrict__ kg, short* __restrict__ vgTg){
  int bh = blockIdx.x; int b = bh / H_, h = bh % H_;
  int t = threadIdx.x;
  #pragma unroll
  for (int it = 0; it < 2; it++){              // kg[bh][64][64]
    int u = it*256 + t; int g = u >> 3, cc = (u & 7)*8;
    int4v val = {};
    if (g < G_) val = *reinterpret_cast<const int4v*>(kbuf + ((size_t)b*N_ + gpos(g))*TD + h*64 + cc);
    *reinterpret_cast<int4v*>(kg + (size_t)bh*4096 + g*64 + cc) = val;
  }
  #pragma unroll
  for (int it = 0; it < 16; it++){             // vgTg[bh][64 d][64 g]
    int u = it*256 + t; int d = u >> 6, g = u & 63;
    short val = 0;
    if (g < G_) val = vT[((size_t)bh*64 + d)*N_ + gpos(g)];
    vgTg[(size_t)bh*4096 + d*64 + g] = val;
  }
}

// ---------------- band + global-key attention (LDS diet, 2 blocks/CU) ------------
__global__ __launch_bounds__(512, 4) void band_attn(
    const short* __restrict__ qb, const short* __restrict__ kbuf, const short* __restrict__ vT,
    const short* __restrict__ kg, const short* __restrict__ vgTg,
    float* __restrict__ out)
{
  __shared__ short sK[448][64];    // rows 0..63 global keys, 64..447 band keys (linear, gload_lds)
  __shared__ short sP[8][16][72];
  // XCD-chunked swizzle: nwg=1536, 192/XCD; adjacent c share 2/3 of K/V band in L2
  int lin = blockIdx.y*128 + blockIdx.x;
  int id = (lin & 7)*192 + (lin >> 3);
  int c = id & 127;
  int bh = id >> 7; int b = bh / H_, h = bh % H_;
  int tid = threadIdx.x, l = tid & 63, w = tid >> 6;
  int cb0 = c*128 - 128;

  // stage K: 56 chunks of 8 rows (1 KB each), 7 per wave
  #pragma unroll
  for (int it = 0; it < 7; it++){
    int ch = w*7 + it;
    int r = ch*8 + (l>>3), cc = (l&7)*8;
    const short* src;
    if (ch < 8){
      src = kg + (size_t)bh*4096 + r*64 + cc;
    } else {
      int ka = cb0 + r - 64;
      ka = ka < 0 ? 0 : (ka > N_-1 ? N_-1 : ka);
      src = kbuf + ((size_t)b*N_ + ka)*TD + h*64 + cc;
    }
    gload16(src, &sK[ch*8][0]);
  }

  int qrow0 = c*128 + w*16;
  v8bf aq[2];
  #pragma unroll
  for (int s = 0; s < 2; s++)
    aq[s] = *reinterpret_cast<const v8bf*>(qb + ((size_t)b*N_ + qrow0 + (l&15))*TD + h*64 + s*32 + (l>>4)*8);

  __syncthreads();

  f32x4 o[4] = {};
  float mrun[4], lrun[4];
  #pragma unroll
  for (int jj = 0; jj < 4; jj++){ mrun[jj] = -1e30f; lrun[jj] = 0.f; }

  int sbase = w >> 2;
  for (int sidx = 0; sidx < 6; sidx++){
    bool isg = (sidx == 0);
    int s0b = (sbase + sidx - 1) * 64;       // band-local window start (valid if !isg)
    int kabs0 = cb0 + s0b;                   // absolute key start (band)
    if (!isg && (kabs0 < 0 || kabs0 >= N_)) continue;   // windows are fully in- or out-of-range
    int rbase = isg ? 0 : 64 + s0b;
    v8bf bkf[4][2];
    #pragma unroll
    for (int kc = 0; kc < 4; kc++)
      #pragma unroll
      for (int s = 0; s < 2; s++)
        bkf[kc][s] = *reinterpret_cast<const v8bf*>(&sK[rbase + kc*16 + (l&15)][s*32 + (l>>4)*8]);
    f32x4 sc[4] = {};
    #pragma unroll
    for (int kc = 0; kc < 4; kc++){
      sc[kc] = mfma16(aq[0], bkf[kc][0], sc[kc]);
      sc[kc] = mfma16(aq[1], bkf[kc][1], sc[kc]);
    }
    // masking (windows are abs-valid unless skipped; only rel + global-pad masks here)
    if (isg){
      if (48 + (l & 15) >= G_){
        #pragma unroll
        for (int jj = 0; jj < 4; jj++) sc[3][jj] = -1e30f;
      }
    } else {
      bool allv = (s0b >= w*16 + 15) && (s0b <= w*16 + 193);
      if (!allv){
        #pragma unroll
        for (int kc = 0; kc < 4; kc++){
          int j_ = s0b + kc*16 + (l & 15);
          #pragma unroll
          for (int jj = 0; jj < 4; jj++){
            int rel = j_ - 128 - (w*16 + (l>>4)*4 + jj);
            if (rel < -128 || rel > 128) sc[kc][jj] = -1e30f;
          }
        }
      }
    }
    // online softmax (wave-parallel, 4 independent q-chains)
    #pragma unroll
    for (int jj = 0; jj < 4; jj++){
      float mk = fmaxf(fmaxf(sc[0][jj], sc[1][jj]), fmaxf(sc[2][jj], sc[3][jj]));
      #pragma unroll
      for (int off = 1; off < 16; off <<= 1) mk = fmaxf(mk, __shfl_xor(mk, off, 64));
      float mnew = fmaxf(mrun[jj], mk);
      float f_ = __expf(mrun[jj] - mnew);
      mrun[jj] = mnew;
      float p0 = __expf(sc[0][jj]-mnew), p1 = __expf(sc[1][jj]-mnew);
      float p2 = __expf(sc[2][jj]-mnew), p3 = __expf(sc[3][jj]-mnew);
      float s_ = (p0+p1)+(p2+p3);
      #pragma unroll
      for (int off = 1; off < 16; off <<= 1) s_ += __shfl_xor(s_, off, 64);
      lrun[jj] = lrun[jj]*f_ + s_;
      #pragma unroll
      for (int cf = 0; cf < 4; cf++) o[cf][jj] *= f_;
      int pr = (l>>4)*4 + jj;
      sP[w][pr][(l&15)]    = f2bf(p0);
      sP[w][pr][16+(l&15)] = f2bf(p1);
      sP[w][pr][32+(l&15)] = f2bf(p2);
      sP[w][pr][48+(l&15)] = f2bf(p3);
    }
    // PV: P from per-wave LDS, V direct from global (L1/L2-shared across waves)
    v8bf ap[2];
    #pragma unroll
    for (int s2 = 0; s2 < 2; s2++)
      ap[s2] = *reinterpret_cast<const v8bf*>(&sP[w][(l&15)][s2*32 + (l>>4)*8]);
    #pragma unroll
    for (int cf = 0; cf < 4; cf++){
      #pragma unroll
      for (int s2 = 0; s2 < 2; s2++){
        const short* vsrc = isg
          ? vgTg + (size_t)bh*4096 + (cf*16 + (l&15))*64 + s2*32 + (l>>4)*8
          : vT + ((size_t)bh*64 + cf*16 + (l&15))*N_ + kabs0 + s2*32 + (l>>4)*8;
        v8bf bv = *reinterpret_cast<const v8bf*>(vsrc);
        o[cf] = mfma16(ap[s2], bv, o[cf]);
      }
    }
  }
  #pragma unroll
  for (int jj = 0; jj < 4; jj++){
    float inv = 1.0f / lrun[jj];
    int n = c*128 + w*16 + (l>>4)*4 + jj;
    int i0 = (n >> 7)*2, j0 = (n & 127)*2;
    #pragma unroll
    for (int cf = 0; cf < 4; cf++){
      float val = o[cf][jj] * inv;
      int t_ = h*64 + cf*16 + (l & 15);
      int cc = t_ >> 2, wi = (t_ >> 1) & 1, wj = t_ & 1;
      out[((b*C_ + cc)*IMG + i0 + wi)*IMG + j0 + wj] = val;
    }
  }
}

// ---------------- global-token attention: split-K flash partials -----------------
__global__ __launch_bounds__(256) void gattn_partial(
    const short* __restrict__ qgb, const short* __restrict__ kga, const short* __restrict__ vgaT,
    float* __restrict__ gpart)
{
  __shared__ short sP[4][64][72];
  int bh = blockIdx.x; int b = bh / H_, h = bh % H_;
  int kc = blockIdx.y;
  int tid = threadIdx.x, l = tid & 63, w = tid >> 6;
  v8bf aq[4][2];
  #pragma unroll
  for (int rf = 0; rf < 4; rf++)
    #pragma unroll
    for (int s = 0; s < 2; s++)
      aq[rf][s] = *reinterpret_cast<const v8bf*>(qgb + (b*64 + rf*16 + (l&15))*TD + h*64 + s*32 + (l>>4)*8);
  f32x4 o[4][4] = {};
  float mrun[4][4], lrun[4][4];
  #pragma unroll
  for (int rf = 0; rf < 4; rf++)
    #pragma unroll
    for (int jj = 0; jj < 4; jj++){ mrun[rf][jj] = -1e30f; lrun[rf][jj] = 0.f; }
  int keybase = kc*1024 + w*256;
  for (int st = 0; st < 4; st++){
    int key0 = keybase + st*64;
    v8bf bkf[4][2];
    #pragma unroll
    for (int kc2 = 0; kc2 < 4; kc2++)
      #pragma unroll
      for (int s = 0; s < 2; s++)
        bkf[kc2][s] = *reinterpret_cast<const v8bf*>(kga + ((size_t)b*N_ + key0 + kc2*16 + (l&15))*TD + h*64 + s*32 + (l>>4)*8);
    #pragma unroll
    for (int rf = 0; rf < 4; rf++){
      f32x4 sc[4] = {};
      #pragma unroll
      for (int kc2 = 0; kc2 < 4; kc2++){
        sc[kc2] = mfma16(aq[rf][0], bkf[kc2][0], sc[kc2]);
        sc[kc2] = mfma16(aq[rf][1], bkf[kc2][1], sc[kc2]);
      }
      #pragma unroll
      for (int jj = 0; jj < 4; jj++){
        float mk = fmaxf(fmaxf(sc[0][jj], sc[1][jj]), fmaxf(sc[2][jj], sc[3][jj]));
        #pragma unroll
        for (int off = 1; off < 16; off <<= 1) mk = fmaxf(mk, __shfl_xor(mk, off, 64));
        float mnew = fmaxf(mrun[rf][jj], mk);
        float f_ = __expf(mrun[rf][jj] - mnew);
        mrun[rf][jj] = mnew;
        float p0 = __expf(sc[0][jj]-mnew), p1 = __expf(sc[1][jj]-mnew);
        float p2 = __expf(sc[2][jj]-mnew), p3 = __expf(sc[3][jj]-mnew);
        float s_ = (p0+p1)+(p2+p3);
        #pragma unroll
        for (int off = 1; off < 16; off <<= 1) s_ += __shfl_xor(s_, off, 64);
        lrun[rf][jj] = lrun[rf][jj]*f_ + s_;
        #pragma unroll
        for (int cf = 0; cf < 4; cf++) o[rf][cf][jj] *= f_;
        int pr = rf*16 + (l>>4)*4 + jj;
        sP[w][pr][(l&15)]    = f2bf(p0);
        sP[w][pr][16+(l&15)] = f2bf(p1);
        sP[w][pr][32+(l&15)] = f2bf(p2);
        sP[w][pr][48+(l&15)] = f2bf(p3);
      }
    }
    #pragma unroll
    for (int cf = 0; cf < 4; cf++){
      #pragma unroll
      for (int s2 = 0; s2 < 2; s2++){
        v8bf bv = *reinterpret_cast<const v8bf*>(vgaT + ((size_t)bh*64 + cf*16 + (l&15))*N_ + key0 + s2*32 + (l>>4)*8);
        #pragma unroll
        for (int rf = 0; rf < 4; rf++){
          v8bf ap = *reinterpret_cast<const v8bf*>(&sP[w][rf*16 + (l&15)][s2*32 + (l>>4)*8]);
          o[rf][cf] = mfma16(ap, bv, o[rf][cf]);
        }
      }
    }
  }
  // partial layout: [q 0..63 M][q 0..63 L][d-major o: d*64 + q]
  float* base = gpart + (size_t)(bh*64 + kc*4 + w) * 4224;
  #pragma unroll
  for (int rf = 0; rf < 4; rf++){
    #pragma unroll
    for (int jj = 0; jj < 4; jj++){
      int q = rf*16 + (l>>4)*4 + jj;
      if ((l & 15) == 0){ base[q] = mrun[rf][jj]; base[64 + q] = lrun[rf][jj]; }
    }
    #pragma unroll
    for (int cf = 0; cf < 4; cf++)
      *reinterpret_cast<f32x4*>(&base[128 + (cf*16 + (l&15))*64 + rf*16 + (l>>4)*4]) = o[rf][cf];
  }
}

// ---------------- combine partials, write GPOS rows ------------------------------
__global__ void gattn_combine(const float* __restrict__ gpart, float* __restrict__ out){
  int bh = blockIdx.x; int b = bh / H_, h = bh % H_;
  int quarter = blockIdx.y;
  int t = threadIdx.x;
  int q = t & 63, dq = t >> 6;
  if (q >= G_) return;
  const float* pb = gpart + (size_t)bh * 64 * 4224;
  float M = -1e30f;
  for (int p = 0; p < 64; p++) M = fmaxf(M, pb[p*4224 + q]);
  float L = 0.f; float acc[4] = {};
  int d0 = quarter*16 + dq*4;
  for (int p = 0; p < 64; p++){
    const float* pp = pb + p*4224;
    float wgt = __expf(pp[q] - M);
    L += pp[64 + q] * wgt;
    #pragma unroll
    for (int e = 0; e < 4; e++) acc[e] += pp[128 + (d0+e)*64 + q] * wgt;
  }
  float invL = 1.0f / L;
  int n = gpos(q);
  int i0 = (n >> 7)*2, j0 = (n & 127)*2;
  #pragma unroll
  for (int e = 0; e < 4; e++){
    int t_ = h*64 + d0 + e;
    int cc = t_ >> 2, wi = (t_ >> 1) & 1, wj = t_ & 1;
    out[((b*C_ + cc)*IMG + i0 + wi)*IMG + j0 + wj] = acc[e] * invL;
  }
}

extern "C" void kernel_launch(void* const* d_in, const int* in_sizes, int n_in,
                              void* d_out, int out_size, void* d_ws, size_t ws_size,
                              hipStream_t stream)
{
  (void)in_sizes; (void)n_in; (void)out_size; (void)ws_size;
  const float* x   = (const float*)d_in[0];
  const float* Wq  = (const float*)d_in[1];  const float* bq  = (const float*)d_in[2];
  const float* Wk  = (const float*)d_in[3];  const float* bk  = (const float*)d_in[4];
  const float* Wv  = (const float*)d_in[5];  const float* bv  = (const float*)d_in[6];
  const float* Wqg = (const float*)d_in[7];  const float* bqg = (const float*)d_in[8];
  const float* Wkg = (const float*)d_in[9];  const float* bkg = (const float*)d_in[10];
  const float* Wvg = (const float*)d_in[11]; const float* bvg = (const float*)d_in[12];
  float* out = (float*)d_out;

  short* ws = (short*)d_ws;
  const size_t SZ = (size_t)B_ * N_ * TD;     // 12,582,912 bf16
  short* tokens  = ws;
  short* Wt      = tokens  + SZ;
  short* tokg    = Wt      + (size_t)6*TD*TD;
  short* qgb     = tokg    + (size_t)128*TD;
  short* qbuf    = qgb     + (size_t)128*TD;
  short* kbuf    = qbuf    + SZ;
  short* vbuf    = kbuf    + SZ;
  short* kgabuf  = vbuf    + SZ;
  short* vgabuf  = kgabuf  + SZ;
  short* vT      = vgabuf  + SZ;
  short* vgaT    = vT      + SZ;
  short* kg      = vgaT    + SZ;
  short* vgTg    = kg      + (size_t)12*64*64;
  // gpart (13 MB) aliases tokens: dead once GEMMs + gathers have run.
  float* gpart   = (float*)tokens;

  prep_w<<<dim3(576,6), dim3(256), 0, stream>>>(Wq, Wk, Wv, Wkg, Wvg, Wqg, Wt);
  tokenize<<<dim3(6144), dim3(256), 0, stream>>>(x, tokens);
  gemm_proj<<<dim3(256,3,5), dim3(256), 0, stream>>>(tokens, Wt, bq, bk, bv, bkg, bvg,
                                                     qbuf, kbuf, vbuf, kgabuf, vgabuf);
  gather_tokg<<<dim3(24), dim3(256), 0, stream>>>(tokens, tokg);
  gemm_qg<<<dim3(3), dim3(256), 0, stream>>>(tokg, Wt, bqg, qgb);
  transpose_v<<<dim3(64,12,2), dim3(256), 0, stream>>>(vbuf, vgabuf, vT, vgaT);
  gather_gkv<<<dim3(12), dim3(256), 0, stream>>>(kbuf, vT, kg, vgTg);
  band_attn<<<dim3(128,12), dim3(512), 0, stream>>>(qbuf, kbuf, vT, kg, vgTg, out);
  gattn_partial<<<dim3(12,16), dim3(256), 0, stream>>>(qgb, kgabuf, vgaT, gpart);
  gattn_combine<<<dim3(12,4), dim3(256), 0, stream>>>(gpart, out);
}